// Round 8
// baseline (161.143 us; speedup 1.0000x reference)
//
#include <hip/hip_runtime.h>

// Chamfer distance loss, two-phase brute force, packed-fp32 VALU.
// N=65536 vertices (x), M=8192 samples (y), D=3.
// Rows: per-n argmin over m via truncated-key uint min (key = qbits&~0x1FFF | m).
// Cols: per-m min over n, float min, norms folded into epilogue.
// q = 0.5*d2 = 0.5||x||^2 + 0.5||y||^2 - x.y as 3 pk_fma (+pk_add seed),
// negated-y precompute. Packed ops pinned via inline asm (v_pk_fma_f32 /
// v_pk_add_f32) -- R6 measured 2.2x instr bloat consistent with scalarized
// elementwise builtins. Row/col blocks interleaved even/odd for CU balance.
// Loop structure identical to R6 (#pragma unroll 2, no manual staging).

constexpr int NP = 65536;
constexpr int MP = 8192;
constexpr int T = 8;                  // points per thread
constexpr int P = T / 2;              // float2 packs per thread
constexpr int NB = NP / (256 * T);    // 32 row-block groups
constexpr int CA = 32;                // m-chunks for rows: LM = 256
constexpr int LM = MP / CA;
constexpr int NBC = MP / (256 * T);   // 4 col-block groups
constexpr int CB = 256;               // n-chunks for cols: LN = 256
constexpr int LN = NP / CB;
constexpr int B1 = NB * CA;           // 1024 row blocks
constexpr int B2 = NBC * CB;          // 1024 col blocks
static_assert(B1 == B2, "even/odd interleave requires B1==B2");

typedef float fv2 __attribute__((ext_vector_type(2)));

__device__ __forceinline__ fv2 pk_fma(fv2 a, fv2 b, fv2 c) {
    fv2 d;
    asm("v_pk_fma_f32 %0, %1, %2, %3" : "=v"(d) : "v"(a), "v"(b), "v"(c));
    return d;
}
__device__ __forceinline__ fv2 pk_add(fv2 a, fv2 b) {
    fv2 d;
    asm("v_pk_add_f32 %0, %1, %2" : "=v"(d) : "v"(a), "v"(b));
    return d;
}
__device__ __forceinline__ unsigned umin32(unsigned a, unsigned b) { return a < b ? a : b; }

// ws layout (bytes):
//   [0,       NP*4)        rowkey  (uint per n: qbits&~0x1FFF | argmin m)
//   [NP*4,    +MP*4)       colbits (uint per m: float bits of min d2, clamped >=0)
//   [+,       +NP*16)      xp (float4: x0,x1,x2, 0.5*||x||^2)
//   [+,       +MP*16)      yp (float4: -y0,-y1,-y2, 0.5*||y||^2)

__global__ __launch_bounds__(256) void k0_init(const float* __restrict__ x,
                                               const float* __restrict__ y,
                                               unsigned* __restrict__ rowkey,
                                               unsigned* __restrict__ colbits,
                                               float4* __restrict__ xp,
                                               float4* __restrict__ yp,
                                               float* __restrict__ out) {
    int i = blockIdx.x * 256 + threadIdx.x;
    if (i < NP) {
        rowkey[i] = 0xFFFFFFFFu;
        float a = x[i * 3 + 0], b = x[i * 3 + 1], c = x[i * 3 + 2];
        xp[i] = make_float4(a, b, c, 0.5f * fmaf(a, a, fmaf(b, b, c * c)));
    }
    if (i < MP) {
        colbits[i] = 0x7F800000u;  // +inf
        float a = y[i * 3 + 0], b = y[i * 3 + 1], c = y[i * 3 + 2];
        yp[i] = make_float4(-a, -b, -c, 0.5f * fmaf(a, a, fmaf(b, b, c * c)));
    }
    if (i == 0) out[0] = 0.f;
}

__global__ __launch_bounds__(256, 6) void k12_pairs(const float4* __restrict__ xp,
                                                    const float4* __restrict__ yp,
                                                    unsigned* __restrict__ rowkey,
                                                    unsigned* __restrict__ colbits) {
    int t = threadIdx.x;
    if ((blockIdx.x & 1) == 0) {
        // ---- rows: 8 n-chains as 4 float2 packs, scan an m-chunk ----
        int b = blockIdx.x >> 1;
        int bx = b & (NB - 1);
        int by = b / NB;
        int nbase = bx * (256 * T);
        fv2 X0[P], X1[P], X2[P], XW[P];
        unsigned kmin[T];
#pragma unroll
        for (int p = 0; p < P; ++p) {
            float4 a = xp[nbase + t + (2 * p) * 256];
            float4 c = xp[nbase + t + (2 * p + 1) * 256];
            X0[p] = fv2{a.x, c.x}; X1[p] = fv2{a.y, c.y};
            X2[p] = fv2{a.z, c.z}; XW[p] = fv2{a.w, c.w};
            kmin[2 * p] = 0xFFFFFFFFu; kmin[2 * p + 1] = 0xFFFFFFFFu;
        }
        int m0 = by * LM;
#pragma unroll 2
        for (int m = m0; m < m0 + LM; ++m) {
            float4 yv = yp[m];  // wave-uniform -> scalar load
            fv2 b0 = {yv.x, yv.x}, b1 = {yv.y, yv.y}, b2 = {yv.z, yv.z};
            fv2 sw = {yv.w, yv.w};
            unsigned mj = (unsigned)m;
#pragma unroll
            for (int p = 0; p < P; ++p) {
                // q = 0.5*d2 >= 0 (tiny-negative keys lose the min: harmless)
                fv2 q = pk_fma(X0[p], b0, pk_fma(X1[p], b1, pk_fma(X2[p], b2, pk_add(XW[p], sw))));
                unsigned klo = (__float_as_uint(q.x) & 0xFFFFE000u) | mj;
                unsigned khi = (__float_as_uint(q.y) & 0xFFFFE000u) | mj;
                kmin[2 * p] = umin32(kmin[2 * p], klo);
                kmin[2 * p + 1] = umin32(kmin[2 * p + 1], khi);
            }
        }
#pragma unroll
        for (int p = 0; p < P; ++p) {
            atomicMin(&rowkey[nbase + t + (2 * p) * 256], kmin[2 * p]);
            atomicMin(&rowkey[nbase + t + (2 * p + 1) * 256], kmin[2 * p + 1]);
        }
    } else {
        // ---- cols: 8 m-chains as 4 float2 packs, scan an n-chunk ----
        int b = blockIdx.x >> 1;
        int bx = b & (NBC - 1);
        int by = b / NBC;
        int mbase = bx * (256 * T);
        fv2 Y0[P], Y1[P], Y2[P], YW[P];
        float dmx[T];
#pragma unroll
        for (int p = 0; p < P; ++p) {
            float4 a = yp[mbase + t + (2 * p) * 256];
            float4 c = yp[mbase + t + (2 * p + 1) * 256];
            Y0[p] = fv2{a.x, c.x}; Y1[p] = fv2{a.y, c.y};
            Y2[p] = fv2{a.z, c.z}; YW[p] = fv2{a.w, c.w};
            dmx[2 * p] = __builtin_inff(); dmx[2 * p + 1] = __builtin_inff();
        }
        int n0 = by * LN;
#pragma unroll 2
        for (int n = n0; n < n0 + LN; ++n) {
            float4 xv = xp[n];  // wave-uniform -> scalar load
            fv2 b0 = {xv.x, xv.x}, b1 = {xv.y, xv.y}, b2 = {xv.z, xv.z};
            fv2 sw = {xv.w, xv.w};
#pragma unroll
            for (int p = 0; p < P; ++p) {
                // q = 0.5||x||^2 - x.y  (0.5||y||^2 folded into epilogue)
                fv2 q = pk_fma(Y0[p], b0, pk_fma(Y1[p], b1, pk_fma(Y2[p], b2, sw)));
                dmx[2 * p] = fminf(dmx[2 * p], q.x);
                dmx[2 * p + 1] = fminf(dmx[2 * p + 1], q.y);
            }
        }
#pragma unroll
        for (int p = 0; p < P; ++p) {
            float dlo = fmaxf(2.f * (dmx[2 * p] + YW[p].x), 0.f);
            float dhi = fmaxf(2.f * (dmx[2 * p + 1] + YW[p].y), 0.f);
            atomicMin(&colbits[mbase + t + (2 * p) * 256], __float_as_uint(dlo));
            atomicMin(&colbits[mbase + t + (2 * p + 1) * 256], __float_as_uint(dhi));
        }
    }
}

__global__ __launch_bounds__(256) void k3_reduce(const unsigned* __restrict__ rowkey,
                                                 const unsigned* __restrict__ colbits,
                                                 const float* __restrict__ probs,
                                                 float* __restrict__ out) {
    int i = blockIdx.x * 256 + threadIdx.x;
    float v = 0.f;
    if (i < NP) {
        unsigned k = rowkey[i];
        unsigned idx = k & 0x1FFFu;
        float dmin = 2.f * __uint_as_float(k & 0xFFFFE000u);  // d2 = 2q
        v = probs[idx] * dmin;  // l2 contribution
    } else {
        int m = i - NP;  // m < MP by grid construction
        float dmin = __uint_as_float(colbits[m]);
        v = probs[m] * dmin;  // l1 contribution
    }
    for (int off = 32; off > 0; off >>= 1) v += __shfl_down(v, off, 64);
    __shared__ float wsum[4];
    int lane = threadIdx.x & 63;
    int w = threadIdx.x >> 6;
    if (lane == 0) wsum[w] = v;
    __syncthreads();
    if (threadIdx.x == 0) {
        atomicAdd(out, wsum[0] + wsum[1] + wsum[2] + wsum[3]);
    }
}

extern "C" void kernel_launch(void* const* d_in, const int* in_sizes, int n_in,
                              void* d_out, int out_size, void* d_ws, size_t ws_size,
                              hipStream_t stream) {
    const float* x = (const float*)d_in[0];      // [N,3]
    const float* y = (const float*)d_in[1];      // [M,3]
    const float* probs = (const float*)d_in[2];  // [M]
    float* out = (float*)d_out;

    char* ws = (char*)d_ws;
    unsigned* rowkey = (unsigned*)ws;
    unsigned* colbits = (unsigned*)(ws + (size_t)NP * 4);
    float4* xp = (float4*)(ws + (size_t)NP * 4 + (size_t)MP * 4);
    float4* yp = (float4*)(ws + (size_t)NP * 4 + (size_t)MP * 4 + (size_t)NP * 16);

    k0_init<<<NP / 256, 256, 0, stream>>>(x, y, rowkey, colbits, xp, yp, out);
    k12_pairs<<<B1 + B2, 256, 0, stream>>>(xp, yp, rowkey, colbits);
    k3_reduce<<<(NP + MP) / 256, 256, 0, stream>>>(rowkey, colbits, probs, out);
}

// Round 9
// 116.963 us; speedup vs baseline: 1.3777x; 1.3777x over previous
//
#include <hip/hip_runtime.h>

// Chamfer distance loss, two-phase brute force, fp32 VALU (R6 structure).
// N=65536 vertices (x), M=8192 samples (y), D=3.
// Rows: per-n argmin over m via truncated-key uint min (key = qbits&~0x1FFF | m).
// Cols: per-m min over n, float min, norms folded into epilogue.
// q = 0.5*d2 = 0.5||x||^2 + 0.5||y||^2 - x.y as 3 fma (+seed add), negated-y
// precompute. fv2 ext-vector chains (compiler may scalarize; scalar fma eats
// the SGPR operand directly -- measured best in R6). NO even/odd interleave
// (regressed R7/R8). This round: finer chunks (CA 64, CB 512) for tail/balance.

constexpr int NP = 65536;
constexpr int MP = 8192;
constexpr int T = 8;                  // points per thread
constexpr int P = T / 2;              // float2 packs per thread
constexpr int NB = NP / (256 * T);    // 32 row-block groups
constexpr int CA = 64;                // m-chunks for rows: LM = 128
constexpr int LM = MP / CA;
constexpr int NBC = MP / (256 * T);   // 4 col-block groups
constexpr int CB = 512;               // n-chunks for cols: LN = 128
constexpr int LN = NP / CB;
constexpr int B1 = NB * CA;           // 2048 row blocks
constexpr int B2 = NBC * CB;          // 2048 col blocks

typedef float fv2 __attribute__((ext_vector_type(2)));

__device__ __forceinline__ fv2 vfma2(fv2 a, fv2 b, fv2 c) {
#if __has_builtin(__builtin_elementwise_fma)
    return __builtin_elementwise_fma(a, b, c);
#else
    fv2 r; r.x = fmaf(a.x, b.x, c.x); r.y = fmaf(a.y, b.y, c.y); return r;
#endif
}
__device__ __forceinline__ fv2 vmin2(fv2 a, fv2 b) {
#if __has_builtin(__builtin_elementwise_min)
    return __builtin_elementwise_min(a, b);
#else
    fv2 r; r.x = fminf(a.x, b.x); r.y = fminf(a.y, b.y); return r;
#endif
}
__device__ __forceinline__ unsigned umin32(unsigned a, unsigned b) { return a < b ? a : b; }

// ws layout (bytes):
//   [0,       NP*4)        rowkey  (uint per n: qbits&~0x1FFF | argmin m)
//   [NP*4,    +MP*4)       colbits (uint per m: float bits of min d2, clamped >=0)
//   [+,       +NP*16)      xp (float4: x0,x1,x2, 0.5*||x||^2)
//   [+,       +MP*16)      yp (float4: -y0,-y1,-y2, 0.5*||y||^2)

__global__ __launch_bounds__(256) void k0_init(const float* __restrict__ x,
                                               const float* __restrict__ y,
                                               unsigned* __restrict__ rowkey,
                                               unsigned* __restrict__ colbits,
                                               float4* __restrict__ xp,
                                               float4* __restrict__ yp,
                                               float* __restrict__ out) {
    int i = blockIdx.x * 256 + threadIdx.x;
    if (i < NP) {
        rowkey[i] = 0xFFFFFFFFu;
        float a = x[i * 3 + 0], b = x[i * 3 + 1], c = x[i * 3 + 2];
        xp[i] = make_float4(a, b, c, 0.5f * fmaf(a, a, fmaf(b, b, c * c)));
    }
    if (i < MP) {
        colbits[i] = 0x7F800000u;  // +inf
        float a = y[i * 3 + 0], b = y[i * 3 + 1], c = y[i * 3 + 2];
        yp[i] = make_float4(-a, -b, -c, 0.5f * fmaf(a, a, fmaf(b, b, c * c)));
    }
    if (i == 0) out[0] = 0.f;
}

__global__ __launch_bounds__(256, 6) void k12_pairs(const float4* __restrict__ xp,
                                                    const float4* __restrict__ yp,
                                                    unsigned* __restrict__ rowkey,
                                                    unsigned* __restrict__ colbits) {
    int t = threadIdx.x;
    if (blockIdx.x < B1) {
        // ---- rows: 8 n-chains as 4 float2 packs, scan an m-chunk ----
        int b = blockIdx.x;
        int bx = b & (NB - 1);
        int by = b / NB;
        int nbase = bx * (256 * T);
        fv2 X0[P], X1[P], X2[P], XW[P];
        unsigned kmin[T];
#pragma unroll
        for (int p = 0; p < P; ++p) {
            float4 a = xp[nbase + t + (2 * p) * 256];
            float4 c = xp[nbase + t + (2 * p + 1) * 256];
            X0[p] = fv2{a.x, c.x}; X1[p] = fv2{a.y, c.y};
            X2[p] = fv2{a.z, c.z}; XW[p] = fv2{a.w, c.w};
            kmin[2 * p] = 0xFFFFFFFFu; kmin[2 * p + 1] = 0xFFFFFFFFu;
        }
        int m0 = by * LM;
#pragma unroll 2
        for (int m = m0; m < m0 + LM; ++m) {
            float4 yv = yp[m];  // wave-uniform -> scalar load
            fv2 b0 = {yv.x, yv.x}, b1 = {yv.y, yv.y}, b2 = {yv.z, yv.z};
            fv2 sw = {yv.w, yv.w};
            unsigned mj = (unsigned)m;
#pragma unroll
            for (int p = 0; p < P; ++p) {
                // q = 0.5*d2 >= 0 (tiny-negative keys lose the min: harmless)
                fv2 q = vfma2(X0[p], b0, vfma2(X1[p], b1, vfma2(X2[p], b2, XW[p] + sw)));
                unsigned klo = (__float_as_uint(q.x) & 0xFFFFE000u) | mj;
                unsigned khi = (__float_as_uint(q.y) & 0xFFFFE000u) | mj;
                kmin[2 * p] = umin32(kmin[2 * p], klo);
                kmin[2 * p + 1] = umin32(kmin[2 * p + 1], khi);
            }
        }
#pragma unroll
        for (int p = 0; p < P; ++p) {
            atomicMin(&rowkey[nbase + t + (2 * p) * 256], kmin[2 * p]);
            atomicMin(&rowkey[nbase + t + (2 * p + 1) * 256], kmin[2 * p + 1]);
        }
    } else {
        // ---- cols: 8 m-chains as 4 float2 packs, scan an n-chunk ----
        int b = blockIdx.x - B1;
        int bx = b & (NBC - 1);
        int by = b / NBC;
        int mbase = bx * (256 * T);
        fv2 Y0[P], Y1[P], Y2[P], YW[P], DM[P];
#pragma unroll
        for (int p = 0; p < P; ++p) {
            float4 a = yp[mbase + t + (2 * p) * 256];
            float4 c = yp[mbase + t + (2 * p + 1) * 256];
            Y0[p] = fv2{a.x, c.x}; Y1[p] = fv2{a.y, c.y};
            Y2[p] = fv2{a.z, c.z}; YW[p] = fv2{a.w, c.w};
            DM[p] = fv2{__builtin_inff(), __builtin_inff()};
        }
        int n0 = by * LN;
#pragma unroll 2
        for (int n = n0; n < n0 + LN; ++n) {
            float4 xv = xp[n];  // wave-uniform -> scalar load
            fv2 b0 = {xv.x, xv.x}, b1 = {xv.y, xv.y}, b2 = {xv.z, xv.z};
            fv2 sw = {xv.w, xv.w};
#pragma unroll
            for (int p = 0; p < P; ++p) {
                // q = 0.5||x||^2 - x.y  (0.5||y||^2 folded into epilogue)
                fv2 q = vfma2(Y0[p], b0, vfma2(Y1[p], b1, vfma2(Y2[p], b2, sw)));
                DM[p] = vmin2(DM[p], q);
            }
        }
#pragma unroll
        for (int p = 0; p < P; ++p) {
            float dlo = fmaxf(2.f * (DM[p].x + YW[p].x), 0.f);
            float dhi = fmaxf(2.f * (DM[p].y + YW[p].y), 0.f);
            atomicMin(&colbits[mbase + t + (2 * p) * 256], __float_as_uint(dlo));
            atomicMin(&colbits[mbase + t + (2 * p + 1) * 256], __float_as_uint(dhi));
        }
    }
}

__global__ __launch_bounds__(256) void k3_reduce(const unsigned* __restrict__ rowkey,
                                                 const unsigned* __restrict__ colbits,
                                                 const float* __restrict__ probs,
                                                 float* __restrict__ out) {
    int i = blockIdx.x * 256 + threadIdx.x;
    float v = 0.f;
    if (i < NP) {
        unsigned k = rowkey[i];
        unsigned idx = k & 0x1FFFu;
        float dmin = 2.f * __uint_as_float(k & 0xFFFFE000u);  // d2 = 2q
        v = probs[idx] * dmin;  // l2 contribution
    } else {
        int m = i - NP;  // m < MP by grid construction
        float dmin = __uint_as_float(colbits[m]);
        v = probs[m] * dmin;  // l1 contribution
    }
    for (int off = 32; off > 0; off >>= 1) v += __shfl_down(v, off, 64);
    __shared__ float wsum[4];
    int lane = threadIdx.x & 63;
    int w = threadIdx.x >> 6;
    if (lane == 0) wsum[w] = v;
    __syncthreads();
    if (threadIdx.x == 0) {
        atomicAdd(out, wsum[0] + wsum[1] + wsum[2] + wsum[3]);
    }
}

extern "C" void kernel_launch(void* const* d_in, const int* in_sizes, int n_in,
                              void* d_out, int out_size, void* d_ws, size_t ws_size,
                              hipStream_t stream) {
    const float* x = (const float*)d_in[0];      // [N,3]
    const float* y = (const float*)d_in[1];      // [M,3]
    const float* probs = (const float*)d_in[2];  // [M]
    float* out = (float*)d_out;

    char* ws = (char*)d_ws;
    unsigned* rowkey = (unsigned*)ws;
    unsigned* colbits = (unsigned*)(ws + (size_t)NP * 4);
    float4* xp = (float4*)(ws + (size_t)NP * 4 + (size_t)MP * 4);
    float4* yp = (float4*)(ws + (size_t)NP * 4 + (size_t)MP * 4 + (size_t)NP * 16);

    k0_init<<<NP / 256, 256, 0, stream>>>(x, y, rowkey, colbits, xp, yp, out);
    k12_pairs<<<B1 + B2, 256, 0, stream>>>(xp, yp, rowkey, colbits);
    k3_reduce<<<(NP + MP) / 256, 256, 0, stream>>>(rowkey, colbits, probs, out);
}